// Round 1
// baseline (1248.029 us; speedup 1.0000x reference)
//
#include <hip/hip_runtime.h>
#include <hip/hip_bf16.h>

#define NN 100000
#define NE 1600000

// ---------------- degree / norm ----------------

__global__ void k_deg_init(float* deg, int n) {
    int i = blockIdx.x * blockDim.x + threadIdx.x;
    if (i < n) deg[i] = 1.0f;  // self-loop contributes 1
}

__global__ void k_deg_count(const int* __restrict__ dst, float* __restrict__ deg, int e) {
    int i = blockIdx.x * blockDim.x + threadIdx.x;
    if (i < e) atomicAdd(&deg[dst[i]], 1.0f);
}

__global__ void k_dinv(float* d, int n) {
    int i = blockIdx.x * blockDim.x + threadIdx.x;
    if (i < n) d[i] = 1.0f / sqrtf(d[i]);  // deg >= 1 always
}

// ---------------- tiny GEMM: [n x 64] @ [64 x M] ----------------

template <int M>
__global__ __launch_bounds__(256) void k_gemm(const float* __restrict__ A,
                                              const float* __restrict__ W,
                                              float* __restrict__ out, int n) {
    __shared__ float sW[64 * M];
    __shared__ float sX[32 * 64];
    for (int i = threadIdx.x; i < 64 * M; i += 256) sW[i] = W[i];
    int row0 = blockIdx.x * 32;
    for (int i = threadIdx.x; i < 32 * 64; i += 256) {
        int r = row0 + (i >> 6);
        sX[i] = (r < n) ? A[(size_t)r * 64 + (i & 63)] : 0.0f;
    }
    __syncthreads();
    for (int idx = threadIdx.x; idx < 32 * M; idx += 256) {
        int r = idx / M, c = idx - r * M;
        float acc = 0.0f;
#pragma unroll
        for (int k = 0; k < 64; ++k) acc += sX[(r << 6) + k] * sW[k * M + c];
        int row = row0 + r;
        if (row < n) out[(size_t)row * M + c] = acc;
    }
}

// ---------------- edge scatter: out[dst] += h[src] * dinv[src]*dinv[dst] ----------------

template <int F>
__global__ __launch_bounds__(256) void k_scatter(const int* __restrict__ src,
                                                 const int* __restrict__ dst,
                                                 const float* __restrict__ dinv,
                                                 const float* __restrict__ h,
                                                 float* __restrict__ out, int e) {
    long long tid = (long long)blockIdx.x * blockDim.x + threadIdx.x;
    if (tid >= (long long)e * F) return;
    int ed = (int)(tid / F);
    int f  = (int)(tid - (long long)ed * F);
    int s = src[ed], d = dst[ed];
    float w = dinv[s] * dinv[d];
    atomicAdd(&out[(size_t)d * F + f], h[(size_t)s * F + f] * w);
}

// ---------------- epilogue: += self-loop + bias, optional ReLU ----------------

template <int F, bool RELU>
__global__ __launch_bounds__(256) void k_finalize(const float* __restrict__ acc,
                                                  const float* __restrict__ h,
                                                  const float* __restrict__ dinv,
                                                  const float* __restrict__ bias,
                                                  float* __restrict__ out, int n) {
    long long tid = (long long)blockIdx.x * blockDim.x + threadIdx.x;
    if (tid >= (long long)n * F) return;
    int i = (int)(tid / F);
    int f = (int)(tid - (long long)i * F);
    float di = dinv[i];
    float v = acc[tid] + h[tid] * di * di + bias[f];
    if (RELU) v = fmaxf(v, 0.0f);
    out[tid] = v;
}

extern "C" void kernel_launch(void* const* d_in, const int* in_sizes, int n_in,
                              void* d_out, int out_size, void* d_ws, size_t ws_size,
                              hipStream_t stream) {
    const float* x  = (const float*)d_in[0];
    const int*   ei = (const int*)d_in[1];   // [2 x E]: row0 = src, row1 = dst
    const float* W1 = (const float*)d_in[2];
    const float* b1 = (const float*)d_in[3];
    const float* W2 = (const float*)d_in[4];
    const float* b2 = (const float*)d_in[5];
    const float* W3 = (const float*)d_in[6];
    const float* b3 = (const float*)d_in[7];
    float* out = (float*)d_out;

    const int* src = ei;
    const int* dst = ei + NE;

    // workspace layout (fp32): dinv[N] | hA[N*64] | hB[N*64]  (~51.6 MB)
    float* dinv = (float*)d_ws;
    float* hA = dinv + 100352;            // N rounded up for alignment
    float* hB = hA + (size_t)NN * 64;

    const int B = 256;
    const int gN   = (NN + B - 1) / B;
    const int gE   = (NE + B - 1) / B;
    const int gNF  = (int)(((long long)NN * 64 + B - 1) / B);
    const int gEF  = (int)(((long long)NE * 64 + B - 1) / B);
    const int gNF3 = (int)(((long long)NN * 40 + B - 1) / B);
    const int gEF3 = (int)(((long long)NE * 40 + B - 1) / B);
    const int gG   = (NN + 31) / 32;

    // ---- norm ----
    k_deg_init<<<gN, B, 0, stream>>>(dinv, NN);
    k_deg_count<<<gE, B, 0, stream>>>(dst, dinv, NE);
    k_dinv<<<gN, B, 0, stream>>>(dinv, NN);

    // ---- layer 1: x @ W1 -> scatter -> +selfloop +b1, ReLU ----
    k_gemm<64><<<gG, B, 0, stream>>>(x, W1, hA, NN);
    hipMemsetAsync(hB, 0, (size_t)NN * 64 * sizeof(float), stream);
    k_scatter<64><<<gEF, B, 0, stream>>>(src, dst, dinv, hA, hB, NE);
    k_finalize<64, true><<<gNF, B, 0, stream>>>(hB, hA, dinv, b1, hB, NN);

    // ---- layer 2 ----
    k_gemm<64><<<gG, B, 0, stream>>>(hB, W2, hA, NN);
    hipMemsetAsync(hB, 0, (size_t)NN * 64 * sizeof(float), stream);
    k_scatter<64><<<gEF, B, 0, stream>>>(src, dst, dinv, hA, hB, NE);
    k_finalize<64, true><<<gNF, B, 0, stream>>>(hB, hA, dinv, b2, hB, NN);

    // ---- layer 3 (M = 40, no ReLU), accumulate directly into d_out ----
    k_gemm<40><<<gG, B, 0, stream>>>(hB, W3, hA, NN);
    hipMemsetAsync(out, 0, (size_t)NN * 40 * sizeof(float), stream);
    k_scatter<40><<<gEF3, B, 0, stream>>>(src, dst, dinv, hA, out, NE);
    k_finalize<40, false><<<gNF3, B, 0, stream>>>(out, hA, dinv, b3, out, NN);
}

// Round 2
// 799.629 us; speedup vs baseline: 1.5608x; 1.5608x over previous
//
#include <hip/hip_runtime.h>
#include <hip/hip_bf16.h>

#define NN 100000
#define NE 1600000
#define NPAD 100352  // NN rounded up to 256 for alignment

// ---------------- CSR build ----------------

__global__ void k_deg_count(const int* __restrict__ dst, int* __restrict__ deg, int e) {
    int i = blockIdx.x * blockDim.x + threadIdx.x;
    if (i < e) atomicAdd(&deg[dst[i]], 1);
}

// Single block of 1024 threads: exclusive scan of deg[0..n) -> rowptr[0..n],
// also emits dinv[i] = rsqrt(deg[i] + 1)  (+1 = self-loop).
__global__ __launch_bounds__(1024) void k_scan(const int* __restrict__ deg,
                                               int* __restrict__ rowptr,
                                               float* __restrict__ dinv, int n) {
    __shared__ int sp[1024];
    int t = threadIdx.x;
    const int CH = (n + 1023) / 1024;
    int beg = t * CH, end = min(beg + CH, n);
    int s = 0;
    for (int i = beg; i < end; ++i) s += deg[i];
    sp[t] = s;
    __syncthreads();
    for (int off = 1; off < 1024; off <<= 1) {
        int v = (t >= off) ? sp[t - off] : 0;
        __syncthreads();
        sp[t] += v;
        __syncthreads();
    }
    int run = (t == 0) ? 0 : sp[t - 1];
    for (int i = beg; i < end; ++i) {
        rowptr[i] = run;
        run += deg[i];
        dinv[i] = rsqrtf((float)(deg[i] + 1));
    }
    if (t == 1023) rowptr[n] = run;  // == E
}

__global__ void k_fill(const int* __restrict__ src, const int* __restrict__ dst,
                       const int* __restrict__ rowptr, int* __restrict__ cursor,
                       const float* __restrict__ dinv, int2* __restrict__ csr, int e) {
    int i = blockIdx.x * blockDim.x + threadIdx.x;
    if (i < e) {
        int d = dst[i], s = src[i];
        int idx = rowptr[d] + atomicAdd(&cursor[d], 1);
        float w = dinv[s] * dinv[d];
        csr[idx] = make_int2(s, __float_as_int(w));
    }
}

// ---------------- tiny GEMM: [n x 64] @ [64 x M] ----------------

template <int M>
__global__ __launch_bounds__(256) void k_gemm(const float* __restrict__ A,
                                              const float* __restrict__ W,
                                              float* __restrict__ out, int n) {
    __shared__ float sW[64 * M];
    __shared__ float sX[32 * 64];
    for (int i = threadIdx.x; i < 64 * M; i += 256) sW[i] = W[i];
    int row0 = blockIdx.x * 32;
    for (int i = threadIdx.x; i < 32 * 64; i += 256) {
        int r = row0 + (i >> 6);
        sX[i] = (r < n) ? A[(size_t)r * 64 + (i & 63)] : 0.0f;
    }
    __syncthreads();
    for (int idx = threadIdx.x; idx < 32 * M; idx += 256) {
        int r = idx / M, c = idx - r * M;
        float acc = 0.0f;
#pragma unroll
        for (int k = 0; k < 64; ++k) acc += sX[(r << 6) + k] * sW[k * M + c];
        int row = row0 + r;
        if (row < n) out[(size_t)row * M + c] = acc;
    }
}

// ---------------- CSR aggregate: one wave per node, lane = feature ----------------
// out[i,f] = sum_j w_j * h[src_j, f] + dinv[i]^2 * h[i,f] + bias[f]   (+ optional ReLU)

template <int F, bool RELU>
__global__ __launch_bounds__(256) void k_aggregate(const int* __restrict__ rowptr,
                                                   const int2* __restrict__ csr,
                                                   const float* __restrict__ h,
                                                   const float* __restrict__ dinv,
                                                   const float* __restrict__ bias,
                                                   float* __restrict__ out, int n) {
    int wave = (int)((blockIdx.x * (size_t)blockDim.x + threadIdx.x) >> 6);
    int lane = threadIdx.x & 63;
    if (wave >= n) return;
    int beg = rowptr[wave], end = rowptr[wave + 1];
    float acc0 = 0.0f, acc1 = 0.0f;
    int j = beg;
    for (; j + 1 < end; j += 2) {
        int2 p0 = csr[j], p1 = csr[j + 1];
        if (lane < F) {
            acc0 += h[(size_t)p0.x * F + lane] * __int_as_float(p0.y);
            acc1 += h[(size_t)p1.x * F + lane] * __int_as_float(p1.y);
        }
    }
    if (j < end) {
        int2 p = csr[j];
        if (lane < F) acc0 += h[(size_t)p.x * F + lane] * __int_as_float(p.y);
    }
    if (lane < F) {
        float di = dinv[wave];
        float v = acc0 + acc1 + h[(size_t)wave * F + lane] * di * di + bias[lane];
        if (RELU) v = fmaxf(v, 0.0f);
        out[(size_t)wave * F + lane] = v;
    }
}

extern "C" void kernel_launch(void* const* d_in, const int* in_sizes, int n_in,
                              void* d_out, int out_size, void* d_ws, size_t ws_size,
                              hipStream_t stream) {
    const float* x  = (const float*)d_in[0];
    const int*   ei = (const int*)d_in[1];   // [2 x E]: row0 = src, row1 = dst
    const float* W1 = (const float*)d_in[2];
    const float* b1 = (const float*)d_in[3];
    const float* W2 = (const float*)d_in[4];
    const float* b2 = (const float*)d_in[5];
    const float* W3 = (const float*)d_in[6];
    const float* b3 = (const float*)d_in[7];
    float* out = (float*)d_out;

    const int* src = ei;
    const int* dst = ei + NE;

    // workspace layout:
    // deg[NPAD] int | rowptr[NPAD] int | cursor[NPAD] int | dinv[NPAD] float |
    // csr[NE] int2 | hA[N*64] float | hB[N*64] float      (~65.6 MB total)
    int*   deg    = (int*)d_ws;
    int*   rowptr = deg + NPAD;
    int*   cursor = rowptr + NPAD;
    float* dinv   = (float*)(cursor + NPAD);
    int2*  csr    = (int2*)(dinv + NPAD);
    float* hA     = (float*)(csr + NE);
    float* hB     = hA + (size_t)NN * 64;

    const int B = 256;
    const int gE = (NE + B - 1) / B;
    const int gG = (NN + 31) / 32;
    const int gW = (NN * 64 + B - 1) / B;  // one wave per node, 4 nodes/block

    // ---- CSR build + norm ----
    hipMemsetAsync(deg, 0, NPAD * sizeof(int), stream);
    hipMemsetAsync(cursor, 0, NPAD * sizeof(int), stream);
    k_deg_count<<<gE, B, 0, stream>>>(dst, deg, NE);
    k_scan<<<1, 1024, 0, stream>>>(deg, rowptr, dinv, NN);
    k_fill<<<gE, B, 0, stream>>>(src, dst, rowptr, cursor, dinv, csr, NE);

    // ---- layer 1 ----
    k_gemm<64><<<gG, B, 0, stream>>>(x, W1, hA, NN);
    k_aggregate<64, true><<<gW, B, 0, stream>>>(rowptr, csr, hA, dinv, b1, hB, NN);

    // ---- layer 2 ----
    k_gemm<64><<<gG, B, 0, stream>>>(hB, W2, hA, NN);
    k_aggregate<64, true><<<gW, B, 0, stream>>>(rowptr, csr, hA, dinv, b2, hB, NN);

    // ---- layer 3 (M = 40, no ReLU) ----
    k_gemm<40><<<gG, B, 0, stream>>>(hB, W3, hA, NN);
    k_aggregate<40, false><<<gW, B, 0, stream>>>(rowptr, csr, hA, dinv, b3, out, NN);
}

// Round 3
// 523.504 us; speedup vs baseline: 2.3840x; 1.5275x over previous
//
#include <hip/hip_runtime.h>
#include <hip/hip_bf16.h>

#define NN 100000
#define NE 1600000
#define NPAD 100352          // NN rounded up to 256
#define NBLK ((NN + 255) / 256)   // 391 blocks -> actually 391? 100000/256 = 390.6 -> 391

// ---------------- CSR build ----------------

__global__ void k_deg_count(const int* __restrict__ dst, int* __restrict__ deg, int e) {
    int i = blockIdx.x * blockDim.x + threadIdx.x;
    if (i < e) atomicAdd(&deg[dst[i]], 1);
}

// hierarchical exclusive scan of deg[0..n) -> rowptr, plus dinv = rsqrt(deg+1)
__global__ __launch_bounds__(256) void k_part(const int* __restrict__ deg,
                                              int* __restrict__ bsum, int n) {
    __shared__ int sp[256];
    int i = blockIdx.x * 256 + threadIdx.x;
    sp[threadIdx.x] = (i < n) ? deg[i] : 0;
    __syncthreads();
    for (int off = 128; off > 0; off >>= 1) {
        if (threadIdx.x < off) sp[threadIdx.x] += sp[threadIdx.x + off];
        __syncthreads();
    }
    if (threadIdx.x == 0) bsum[blockIdx.x] = sp[0];
}

__global__ __launch_bounds__(512) void k_top(const int* __restrict__ bsum,
                                             int* __restrict__ boff, int nb,
                                             int* __restrict__ rowptr, int n, int e) {
    __shared__ int sp[512];
    int t = threadIdx.x;
    int v = (t < nb) ? bsum[t] : 0;
    sp[t] = v;
    __syncthreads();
    for (int off = 1; off < 512; off <<= 1) {
        int u = (t >= off) ? sp[t - off] : 0;
        __syncthreads();
        sp[t] += u;
        __syncthreads();
    }
    if (t < nb) boff[t] = sp[t] - v;      // exclusive block offset
    if (t == 0) rowptr[n] = e;
}

__global__ __launch_bounds__(256) void k_write(const int* __restrict__ deg,
                                               const int* __restrict__ boff,
                                               int* __restrict__ rowptr,
                                               float* __restrict__ dinv, int n) {
    __shared__ int sp[256];
    int t = threadIdx.x;
    int i = blockIdx.x * 256 + t;
    int d = (i < n) ? deg[i] : 0;
    sp[t] = d;
    __syncthreads();
    for (int off = 1; off < 256; off <<= 1) {
        int u = (t >= off) ? sp[t - off] : 0;
        __syncthreads();
        sp[t] += u;
        __syncthreads();
    }
    if (i < n) {
        rowptr[i] = boff[blockIdx.x] + sp[t] - d;   // exclusive
        dinv[i] = rsqrtf((float)(d + 1));           // +1 = self-loop
    }
}

__global__ void k_fill(const int* __restrict__ src, const int* __restrict__ dst,
                       const int* __restrict__ rowptr, int* __restrict__ cursor,
                       const float* __restrict__ dinv, int2* __restrict__ csr, int e) {
    int i = blockIdx.x * blockDim.x + threadIdx.x;
    if (i < e) {
        int d = dst[i], s = src[i];
        int idx = rowptr[d] + atomicAdd(&cursor[d], 1);
        float w = dinv[s] * dinv[d];
        csr[idx] = make_int2(s, __float_as_int(w));
    }
}

// ---------------- tiny GEMM: [n x 64] @ [64 x M] ----------------

template <int M>
__global__ __launch_bounds__(256) void k_gemm(const float* __restrict__ A,
                                              const float* __restrict__ W,
                                              float* __restrict__ out, int n) {
    __shared__ float sW[64 * M];
    __shared__ float sX[32 * 64];
    for (int i = threadIdx.x; i < 64 * M; i += 256) sW[i] = W[i];
    int row0 = blockIdx.x * 32;
    for (int i = threadIdx.x; i < 32 * 64; i += 256) {
        int r = row0 + (i >> 6);
        sX[i] = (r < n) ? A[(size_t)r * 64 + (i & 63)] : 0.0f;
    }
    __syncthreads();
    for (int idx = threadIdx.x; idx < 32 * M; idx += 256) {
        int r = idx / M, c = idx - r * M;
        float acc = 0.0f;
#pragma unroll
        for (int k = 0; k < 64; ++k) acc += sX[(r << 6) + k] * sW[k * M + c];
        int row = row0 + r;
        if (row < n) out[(size_t)row * M + c] = acc;
    }
}

// ---------------- CSR aggregate, F=64, float4-wide ----------------
// One wave per node. 16 lanes x float4 cover the 64 features of one edge;
// 4 edges (lane groups) in flight per iteration; butterfly reduce at the end.

template <bool RELU>
__global__ __launch_bounds__(256) void k_aggregate64(const int* __restrict__ rowptr,
                                                     const int2* __restrict__ csr,
                                                     const float* __restrict__ h,
                                                     const float* __restrict__ dinv,
                                                     const float* __restrict__ bias,
                                                     float* __restrict__ out, int n) {
    int wave = (int)((blockIdx.x * (size_t)blockDim.x + threadIdx.x) >> 6);
    int lane = threadIdx.x & 63;
    if (wave >= n) return;
    int beg = rowptr[wave], end = rowptr[wave + 1];
    int eg = lane >> 4;   // edge slot 0..3
    int fl = lane & 15;   // float4 slot 0..15
    float4 acc = make_float4(0.f, 0.f, 0.f, 0.f);
    for (int j = beg; j < end; j += 4) {
        int jj = j + eg;
        if (jj < end) {
            int2 p = csr[jj];
            float w = __int_as_float(p.y);
            const float4 hv = *(const float4*)(h + (size_t)p.x * 64 + fl * 4);
            acc.x += hv.x * w; acc.y += hv.y * w;
            acc.z += hv.z * w; acc.w += hv.w * w;
        }
    }
    // sum the 4 edge groups (lanes differing in bits 4 and 5)
#pragma unroll
    for (int m = 16; m <= 32; m <<= 1) {
        acc.x += __shfl_xor(acc.x, m);
        acc.y += __shfl_xor(acc.y, m);
        acc.z += __shfl_xor(acc.z, m);
        acc.w += __shfl_xor(acc.w, m);
    }
    if (eg == 0) {
        float di = dinv[wave], di2 = di * di;
        const float4 hv = *(const float4*)(h + (size_t)wave * 64 + fl * 4);
        const float4 bv = *(const float4*)(bias + fl * 4);
        float4 v;
        v.x = acc.x + hv.x * di2 + bv.x;
        v.y = acc.y + hv.y * di2 + bv.y;
        v.z = acc.z + hv.z * di2 + bv.z;
        v.w = acc.w + hv.w * di2 + bv.w;
        if (RELU) {
            v.x = fmaxf(v.x, 0.f); v.y = fmaxf(v.y, 0.f);
            v.z = fmaxf(v.z, 0.f); v.w = fmaxf(v.w, 0.f);
        }
        *(float4*)(out + (size_t)wave * 64 + fl * 4) = v;
    }
}

// ---------------- CSR aggregate, generic scalar (used for F=40) ----------------

template <int F, bool RELU>
__global__ __launch_bounds__(256) void k_aggregate(const int* __restrict__ rowptr,
                                                   const int2* __restrict__ csr,
                                                   const float* __restrict__ h,
                                                   const float* __restrict__ dinv,
                                                   const float* __restrict__ bias,
                                                   float* __restrict__ out, int n) {
    int wave = (int)((blockIdx.x * (size_t)blockDim.x + threadIdx.x) >> 6);
    int lane = threadIdx.x & 63;
    if (wave >= n) return;
    int beg = rowptr[wave], end = rowptr[wave + 1];
    float acc0 = 0.0f, acc1 = 0.0f;
    int j = beg;
    for (; j + 1 < end; j += 2) {
        int2 p0 = csr[j], p1 = csr[j + 1];
        if (lane < F) {
            acc0 += h[(size_t)p0.x * F + lane] * __int_as_float(p0.y);
            acc1 += h[(size_t)p1.x * F + lane] * __int_as_float(p1.y);
        }
    }
    if (j < end) {
        int2 p = csr[j];
        if (lane < F) acc0 += h[(size_t)p.x * F + lane] * __int_as_float(p.y);
    }
    if (lane < F) {
        float di = dinv[wave];
        float v = acc0 + acc1 + h[(size_t)wave * F + lane] * di * di + bias[lane];
        if (RELU) v = fmaxf(v, 0.0f);
        out[(size_t)wave * F + lane] = v;
    }
}

extern "C" void kernel_launch(void* const* d_in, const int* in_sizes, int n_in,
                              void* d_out, int out_size, void* d_ws, size_t ws_size,
                              hipStream_t stream) {
    const float* x  = (const float*)d_in[0];
    const int*   ei = (const int*)d_in[1];   // [2 x E]: row0 = src, row1 = dst
    const float* W1 = (const float*)d_in[2];
    const float* b1 = (const float*)d_in[3];
    const float* W2 = (const float*)d_in[4];
    const float* b2 = (const float*)d_in[5];
    const float* W3 = (const float*)d_in[6];
    const float* b3 = (const float*)d_in[7];
    float* out = (float*)d_out;

    const int* src = ei;
    const int* dst = ei + NE;

    // workspace layout:
    // deg[NPAD] | rowptr[NPAD] | cursor[NPAD] | bsum[512] | boff[512] (ints)
    // dinv[NPAD] (float) | csr[NE] (int2) | hA[N*64] | hB[N*64] (float)
    int*   deg    = (int*)d_ws;
    int*   rowptr = deg + NPAD;
    int*   cursor = rowptr + NPAD;
    int*   bsum   = cursor + NPAD;
    int*   boff   = bsum + 512;
    float* dinv   = (float*)(boff + 512);
    int2*  csr    = (int2*)(dinv + NPAD);
    float* hA     = (float*)(csr + NE);
    float* hB     = hA + (size_t)NN * 64;

    const int B = 256;
    const int gE = (NE + B - 1) / B;
    const int gG = (NN + 31) / 32;
    const int gW = (NN * 64 + B - 1) / B;  // one wave per node
    const int nb = (NN + 255) / 256;       // scan blocks

    // ---- CSR build + norm ----
    hipMemsetAsync(deg, 0, NPAD * sizeof(int), stream);
    hipMemsetAsync(cursor, 0, NPAD * sizeof(int), stream);
    k_deg_count<<<gE, B, 0, stream>>>(dst, deg, NE);
    k_part<<<nb, 256, 0, stream>>>(deg, bsum, NN);
    k_top<<<1, 512, 0, stream>>>(bsum, boff, nb, rowptr, NN, NE);
    k_write<<<nb, 256, 0, stream>>>(deg, boff, rowptr, dinv, NN);
    k_fill<<<gE, B, 0, stream>>>(src, dst, rowptr, cursor, dinv, csr, NE);

    // ---- layer 1 ----
    k_gemm<64><<<gG, B, 0, stream>>>(x, W1, hA, NN);
    k_aggregate64<true><<<gW, B, 0, stream>>>(rowptr, csr, hA, dinv, b1, hB, NN);

    // ---- layer 2 ----
    k_gemm<64><<<gG, B, 0, stream>>>(hB, W2, hA, NN);
    k_aggregate64<true><<<gW, B, 0, stream>>>(rowptr, csr, hA, dinv, b2, hB, NN);

    // ---- layer 3 (M = 40, no ReLU) ----
    k_gemm<40><<<gG, B, 0, stream>>>(hB, W3, hA, NN);
    k_aggregate<40, false><<<gW, B, 0, stream>>>(rowptr, csr, hA, dinv, b3, out, NN);
}

// Round 4
// 459.080 us; speedup vs baseline: 2.7185x; 1.1403x over previous
//
#include <hip/hip_runtime.h>
#include <hip/hip_bf16.h>

#define NN 100000
#define NE 1600000
#define NPAD 100352          // NN rounded up to 256

// ---------------- CSR build ----------------

__global__ void k_deg_count(const int* __restrict__ dst, int* __restrict__ deg, int e) {
    int i = blockIdx.x * blockDim.x + threadIdx.x;
    if (i < e) atomicAdd(&deg[dst[i]], 1);
}

// hierarchical exclusive scan of deg[0..n) -> rowptr, plus dinv = rsqrt(deg+1)
__global__ __launch_bounds__(256) void k_part(const int* __restrict__ deg,
                                              int* __restrict__ bsum, int n) {
    __shared__ int sp[256];
    int i = blockIdx.x * 256 + threadIdx.x;
    sp[threadIdx.x] = (i < n) ? deg[i] : 0;
    __syncthreads();
    for (int off = 128; off > 0; off >>= 1) {
        if (threadIdx.x < off) sp[threadIdx.x] += sp[threadIdx.x + off];
        __syncthreads();
    }
    if (threadIdx.x == 0) bsum[blockIdx.x] = sp[0];
}

__global__ __launch_bounds__(512) void k_top(const int* __restrict__ bsum,
                                             int* __restrict__ boff, int nb,
                                             int* __restrict__ rowptr, int n, int e) {
    __shared__ int sp[512];
    int t = threadIdx.x;
    int v = (t < nb) ? bsum[t] : 0;
    sp[t] = v;
    __syncthreads();
    for (int off = 1; off < 512; off <<= 1) {
        int u = (t >= off) ? sp[t - off] : 0;
        __syncthreads();
        sp[t] += u;
        __syncthreads();
    }
    if (t < nb) boff[t] = sp[t] - v;      // exclusive block offset
    if (t == 0) rowptr[n] = e;
}

__global__ __launch_bounds__(256) void k_write(const int* __restrict__ deg,
                                               const int* __restrict__ boff,
                                               int* __restrict__ rowptr,
                                               float* __restrict__ dinv, int n) {
    __shared__ int sp[256];
    int t = threadIdx.x;
    int i = blockIdx.x * 256 + t;
    int d = (i < n) ? deg[i] : 0;
    sp[t] = d;
    __syncthreads();
    for (int off = 1; off < 256; off <<= 1) {
        int u = (t >= off) ? sp[t - off] : 0;
        __syncthreads();
        sp[t] += u;
        __syncthreads();
    }
    if (i < n) {
        rowptr[i] = boff[blockIdx.x] + sp[t] - d;   // exclusive
        dinv[i] = rsqrtf((float)(d + 1));           // +1 = self-loop
    }
}

__global__ void k_fill(const int* __restrict__ src, const int* __restrict__ dst,
                       const int* __restrict__ rowptr, int* __restrict__ cursor,
                       const float* __restrict__ dinv, int2* __restrict__ csr, int e) {
    int i = blockIdx.x * blockDim.x + threadIdx.x;
    if (i < e) {
        int d = dst[i], s = src[i];
        int idx = rowptr[d] + atomicAdd(&cursor[d], 1);
        float w = dinv[s] * dinv[d];
        csr[idx] = make_int2(s, __float_as_int(w));
    }
}

// ---------------- register-blocked GEMM: [n x 64] @ [64 x M] (+bias) ----------------
// 32 rows per block; thread computes 2 rows x 4 cols.

template <int M, bool BIAS>
__global__ __launch_bounds__(256) void k_gemm(const float* __restrict__ A,
                                              const float* __restrict__ W,
                                              const float* __restrict__ bias,
                                              float* __restrict__ out, int n) {
    __shared__ float sX[32 * 64];
    __shared__ float sW[64 * M];
    int row0 = blockIdx.x * 32;
    for (int i = threadIdx.x; i < 16 * M; i += 256)
        ((float4*)sW)[i] = ((const float4*)W)[i];
    for (int i = threadIdx.x; i < 32 * 16; i += 256) {
        int r = i >> 4, c4 = i & 15;
        int row = row0 + r;
        float4 v = (row < n) ? ((const float4*)(A + ((size_t)row << 6)))[c4]
                             : make_float4(0.f, 0.f, 0.f, 0.f);
        ((float4*)sX)[i] = v;
    }
    __syncthreads();

    constexpr int CD = M / 4;             // col groups of 4
    int ci = (threadIdx.x % CD) * 4;
    int rg = threadIdx.x / CD;            // row group (2 rows each)
    if (rg < 16) {
        int r0 = rg * 2;
        float acc[2][4] = {};
#pragma unroll
        for (int k = 0; k < 64; ++k) {
            float a0 = sX[(r0 << 6) + k];
            float a1 = sX[((r0 + 1) << 6) + k];
            float4 w = *(const float4*)&sW[k * M + ci];
            acc[0][0] += a0 * w.x; acc[0][1] += a0 * w.y;
            acc[0][2] += a0 * w.z; acc[0][3] += a0 * w.w;
            acc[1][0] += a1 * w.x; acc[1][1] += a1 * w.y;
            acc[1][2] += a1 * w.z; acc[1][3] += a1 * w.w;
        }
        float4 bv = make_float4(0.f, 0.f, 0.f, 0.f);
        if (BIAS) bv = *(const float4*)(bias + ci);
#pragma unroll
        for (int rr = 0; rr < 2; ++rr) {
            int row = row0 + r0 + rr;
            if (row < n) {
                float4 v = make_float4(acc[rr][0] + bv.x, acc[rr][1] + bv.y,
                                       acc[rr][2] + bv.z, acc[rr][3] + bv.w);
                *(float4*)(out + (size_t)row * M + ci) = v;
            }
        }
    }
}

// ---------------- CSR aggregate (F=64), optional fused epilogue matvec ----------------
// MODE 0: out = agg            (64 feats)
// MODE 1: out = relu(agg + b)  (64 feats)
// MODE 2: out = relu(agg + b) @ Wn   (64x64 matvec fused, Wn in LDS)
// agg includes the self-loop term dinv[i]^2 * h[i].

template <int MODE>
__global__ __launch_bounds__(256) void k_agg(const int* __restrict__ rowptr,
                                             const int2* __restrict__ csr,
                                             const float* __restrict__ h,
                                             const float* __restrict__ dinv,
                                             const float* __restrict__ bias,
                                             const float* __restrict__ Wn,
                                             float* __restrict__ out, int n) {
    __shared__ float sW[64 * 64];
    __shared__ float sV[4][64];
    if (MODE == 2) {
        for (int i = threadIdx.x; i < 1024; i += 256)
            ((float4*)sW)[i] = ((const float4*)Wn)[i];
        __syncthreads();
    }
    int wid = threadIdx.x >> 6, lane = threadIdx.x & 63;
    int node = blockIdx.x * 4 + wid;
    if (node >= n) return;
    int beg = rowptr[node], end = rowptr[node + 1];
    int eg = lane >> 4;       // edge slot 0..3
    int fl = lane & 15;       // float4 slot 0..15
    float4 a0 = make_float4(0.f, 0.f, 0.f, 0.f);
    float4 a1 = make_float4(0.f, 0.f, 0.f, 0.f);
    int j = beg + eg;
    for (; j + 4 < end; j += 8) {            // 8 edges/wave-iter, 2 gathers in flight
        int2 p0 = csr[j], p1 = csr[j + 4];
        float w0 = __int_as_float(p0.y), w1 = __int_as_float(p1.y);
        float4 h0 = *(const float4*)(h + ((size_t)p0.x << 6) + (fl << 2));
        float4 h1 = *(const float4*)(h + ((size_t)p1.x << 6) + (fl << 2));
        a0.x += h0.x * w0; a0.y += h0.y * w0; a0.z += h0.z * w0; a0.w += h0.w * w0;
        a1.x += h1.x * w1; a1.y += h1.y * w1; a1.z += h1.z * w1; a1.w += h1.w * w1;
    }
    if (j < end) {
        int2 p = csr[j];
        float w = __int_as_float(p.y);
        float4 hv = *(const float4*)(h + ((size_t)p.x << 6) + (fl << 2));
        a0.x += hv.x * w; a0.y += hv.y * w; a0.z += hv.z * w; a0.w += hv.w * w;
    }
    a0.x += a1.x; a0.y += a1.y; a0.z += a1.z; a0.w += a1.w;
#pragma unroll
    for (int m = 16; m <= 32; m <<= 1) {
        a0.x += __shfl_xor(a0.x, m); a0.y += __shfl_xor(a0.y, m);
        a0.z += __shfl_xor(a0.z, m); a0.w += __shfl_xor(a0.w, m);
    }
    if (eg == 0) {
        float di = dinv[node], di2 = di * di;
        float4 hv = *(const float4*)(h + ((size_t)node << 6) + (fl << 2));
        a0.x += hv.x * di2; a0.y += hv.y * di2;
        a0.z += hv.z * di2; a0.w += hv.w * di2;
        if (MODE >= 1) {
            float4 bv = *(const float4*)(bias + (fl << 2));
            a0.x = fmaxf(a0.x + bv.x, 0.f); a0.y = fmaxf(a0.y + bv.y, 0.f);
            a0.z = fmaxf(a0.z + bv.z, 0.f); a0.w = fmaxf(a0.w + bv.w, 0.f);
        }
        if (MODE == 2) {
            *(float4*)&sV[wid][fl << 2] = a0;
        } else {
            *(float4*)(out + ((size_t)node << 6) + (fl << 2)) = a0;
        }
    }
    if (MODE == 2) {
        // in-wave ds_write -> ds_read: DS ops complete in order per wave; make it airtight
        asm volatile("s_waitcnt lgkmcnt(0)" ::: "memory");
        float acc = 0.f;
#pragma unroll
        for (int kk = 0; kk < 16; ++kk) {
            float4 v4 = *(const float4*)&sV[wid][kk << 2];
            acc += v4.x * sW[(kk * 4 + 0) * 64 + lane];
            acc += v4.y * sW[(kk * 4 + 1) * 64 + lane];
            acc += v4.z * sW[(kk * 4 + 2) * 64 + lane];
            acc += v4.w * sW[(kk * 4 + 3) * 64 + lane];
        }
        out[((size_t)node << 6) + lane] = acc;
    }
}

extern "C" void kernel_launch(void* const* d_in, const int* in_sizes, int n_in,
                              void* d_out, int out_size, void* d_ws, size_t ws_size,
                              hipStream_t stream) {
    const float* x  = (const float*)d_in[0];
    const int*   ei = (const int*)d_in[1];   // [2 x E]: row0 = src, row1 = dst
    const float* W1 = (const float*)d_in[2];
    const float* b1 = (const float*)d_in[3];
    const float* W2 = (const float*)d_in[4];
    const float* b2 = (const float*)d_in[5];
    const float* W3 = (const float*)d_in[6];
    const float* b3 = (const float*)d_in[7];
    float* out = (float*)d_out;

    const int* src = ei;
    const int* dst = ei + NE;

    // workspace layout:
    // deg[NPAD] | rowptr[NPAD] | cursor[NPAD] | bsum[512] | boff[512] (ints)
    // dinv[NPAD] (float) | csr[NE] (int2) | hA[N*64] | hB[N*64] (float)
    int*   deg    = (int*)d_ws;
    int*   rowptr = deg + NPAD;
    int*   cursor = rowptr + NPAD;
    int*   bsum   = cursor + NPAD;
    int*   boff   = bsum + 512;
    float* dinv   = (float*)(boff + 512);
    int2*  csr    = (int2*)(dinv + NPAD);
    float* hA     = (float*)(csr + NE);
    float* hB     = hA + (size_t)NN * 64;

    const int B = 256;
    const int gE = (NE + B - 1) / B;
    const int gG = (NN + 31) / 32;
    const int gA = (NN + 3) / 4;          // 4 nodes (waves) per block
    const int nb = (NN + 255) / 256;      // scan blocks

    // ---- CSR build + norm ----
    hipMemsetAsync(deg, 0, NPAD * sizeof(int), stream);
    hipMemsetAsync(cursor, 0, NPAD * sizeof(int), stream);
    k_deg_count<<<gE, B, 0, stream>>>(dst, deg, NE);
    k_part<<<nb, 256, 0, stream>>>(deg, bsum, NN);
    k_top<<<1, 512, 0, stream>>>(bsum, boff, nb, rowptr, NN, NE);
    k_write<<<nb, 256, 0, stream>>>(deg, boff, rowptr, dinv, NN);
    k_fill<<<gE, B, 0, stream>>>(src, dst, rowptr, cursor, dinv, csr, NE);

    // ---- layer 1 GEMM: h1pre = x @ W1 ----
    k_gemm<64, false><<<gG, B, 0, stream>>>(x, W1, nullptr, hA, NN);
    // ---- AGG1 fused: hB = relu(agg(h1pre) + b1) @ W2   (= h2pre) ----
    k_agg<2><<<gA, B, 0, stream>>>(rowptr, csr, hA, dinv, b1, W2, hB, NN);
    // ---- AGG2: hA = relu(agg(h2pre) + b2)   (= h2) ----
    k_agg<1><<<gA, B, 0, stream>>>(rowptr, csr, hB, dinv, b2, nullptr, hA, NN);
    // ---- AGG3 (layer-3 aggregate BEFORE its GEMM): hB = agg(h2) ----
    k_agg<0><<<gA, B, 0, stream>>>(rowptr, csr, hA, dinv, nullptr, nullptr, hB, NN);
    // ---- layer 3 GEMM: out = hB @ W3 + b3 ----
    k_gemm<40, true><<<gG, B, 0, stream>>>(hB, W3, b3, out, NN);
}

// Round 5
// 422.230 us; speedup vs baseline: 2.9558x; 1.0873x over previous
//
#include <hip/hip_runtime.h>
#include <hip/hip_fp16.h>

#define NN 100000
#define NE 1600000
#define NPAD 100352          // NN rounded up to 256

// ---------------- CSR build ----------------

__global__ void k_deg_count(const int* __restrict__ dst, int* __restrict__ deg, int e) {
    int i = blockIdx.x * blockDim.x + threadIdx.x;
    if (i < e) atomicAdd(&deg[dst[i]], 1);
}

__global__ __launch_bounds__(256) void k_part(const int* __restrict__ deg,
                                              int* __restrict__ bsum, int n) {
    __shared__ int sp[256];
    int i = blockIdx.x * 256 + threadIdx.x;
    sp[threadIdx.x] = (i < n) ? deg[i] : 0;
    __syncthreads();
    for (int off = 128; off > 0; off >>= 1) {
        if (threadIdx.x < off) sp[threadIdx.x] += sp[threadIdx.x + off];
        __syncthreads();
    }
    if (threadIdx.x == 0) bsum[blockIdx.x] = sp[0];
}

__global__ __launch_bounds__(512) void k_top(const int* __restrict__ bsum,
                                             int* __restrict__ boff, int nb,
                                             int* __restrict__ rowptr, int n, int e) {
    __shared__ int sp[512];
    int t = threadIdx.x;
    int v = (t < nb) ? bsum[t] : 0;
    sp[t] = v;
    __syncthreads();
    for (int off = 1; off < 512; off <<= 1) {
        int u = (t >= off) ? sp[t - off] : 0;
        __syncthreads();
        sp[t] += u;
        __syncthreads();
    }
    if (t < nb) boff[t] = sp[t] - v;
    if (t == 0) rowptr[n] = e;
}

__global__ __launch_bounds__(256) void k_write(const int* __restrict__ deg,
                                               const int* __restrict__ boff,
                                               int* __restrict__ rowptr,
                                               float* __restrict__ dinv, int n) {
    __shared__ int sp[256];
    int t = threadIdx.x;
    int i = blockIdx.x * 256 + t;
    int d = (i < n) ? deg[i] : 0;
    sp[t] = d;
    __syncthreads();
    for (int off = 1; off < 256; off <<= 1) {
        int u = (t >= off) ? sp[t - off] : 0;
        __syncthreads();
        sp[t] += u;
        __syncthreads();
    }
    if (i < n) {
        rowptr[i] = boff[blockIdx.x] + sp[t] - d;   // exclusive
        dinv[i] = rsqrtf((float)(d + 1));           // +1 = self-loop
    }
}

__global__ void k_fill(const int* __restrict__ src, const int* __restrict__ dst,
                       const int* __restrict__ rowptr, int* __restrict__ cursor,
                       int* __restrict__ csr_src, int e) {
    int i = blockIdx.x * blockDim.x + threadIdx.x;
    if (i < e) {
        int d = dst[i];
        int idx = rowptr[d] + atomicAdd(&cursor[d], 1);
        csr_src[idx] = src[i];
    }
}

// ---------------- layer-1 GEMM: g1 = fp16( dinv .* (x @ W1) ) ----------------
// 32 rows/block; thread computes 2 rows x 4 cols.

__global__ __launch_bounds__(256) void k_gemm1(const float* __restrict__ A,
                                               const float* __restrict__ W,
                                               const float* __restrict__ dinv,
                                               __half* __restrict__ out, int n) {
    __shared__ float sX[32 * 64];
    __shared__ float sW[64 * 64];
    int row0 = blockIdx.x * 32;
    for (int i = threadIdx.x; i < 16 * 64; i += 256)
        ((float4*)sW)[i] = ((const float4*)W)[i];
    for (int i = threadIdx.x; i < 32 * 16; i += 256) {
        int r = i >> 4, c4 = i & 15;
        int row = row0 + r;
        float4 v = (row < n) ? ((const float4*)(A + ((size_t)row << 6)))[c4]
                             : make_float4(0.f, 0.f, 0.f, 0.f);
        ((float4*)sX)[i] = v;
    }
    __syncthreads();

    int ci = (threadIdx.x & 15) * 4;
    int r0 = (threadIdx.x >> 4) * 2;
    float acc[2][4] = {};
#pragma unroll
    for (int k = 0; k < 64; ++k) {
        float a0 = sX[(r0 << 6) + k];
        float a1 = sX[((r0 + 1) << 6) + k];
        float4 w = *(const float4*)&sW[(k << 6) + ci];
        acc[0][0] += a0 * w.x; acc[0][1] += a0 * w.y;
        acc[0][2] += a0 * w.z; acc[0][3] += a0 * w.w;
        acc[1][0] += a1 * w.x; acc[1][1] += a1 * w.y;
        acc[1][2] += a1 * w.z; acc[1][3] += a1 * w.w;
    }
#pragma unroll
    for (int rr = 0; rr < 2; ++rr) {
        int row = row0 + r0 + rr;
        if (row < n) {
            float di = dinv[row];
            union { uint2 u; __half2 h[2]; } P;
            P.h[0] = __float22half2_rn(make_float2(acc[rr][0] * di, acc[rr][1] * di));
            P.h[1] = __float22half2_rn(make_float2(acc[rr][2] * di, acc[rr][3] * di));
            *(uint2*)(out + ((size_t)row << 6) + ci) = P.u;
        }
    }
}

// ---------------- CSR aggregate over fp16 g-rows ----------------
// t[d] = sum_{j in N(d)} g[s_j] + g[d]   (g = dinv .* h, so dinv[d]*t is the GCN agg)
// MODE 1: gout = fp16( relu(dinv*t + bias) * dinv )                 (prep next layer)
// MODE 2: h = relu(dinv*t + bias); gout = fp16( (h @ Wn) * dinv )   (fused 64x64 GEMM)
// MODE 3: fout = (dinv*t) @ Wn + bias2                              (fused 64x40 GEMM)
// Lane map: 8 edge slots (eg) x 8 lanes (fl); each lane loads half8 = 16 B.

#define ACC8(r) { \
    const __half2* hh_ = (const __half2*)&(r); \
    float2 f_; \
    f_ = __half22float2(hh_[0]); a[0].x += f_.x; a[0].y += f_.y; \
    f_ = __half22float2(hh_[1]); a[1].x += f_.x; a[1].y += f_.y; \
    f_ = __half22float2(hh_[2]); a[2].x += f_.x; a[2].y += f_.y; \
    f_ = __half22float2(hh_[3]); a[3].x += f_.x; a[3].y += f_.y; }

template <int MODE>
__global__ __launch_bounds__(256) void k_agg(const int* __restrict__ rowptr,
                                             const int* __restrict__ csr_src,
                                             const __half* __restrict__ g,
                                             const float* __restrict__ dinv,
                                             const float* __restrict__ bias,
                                             const float* __restrict__ Wn,
                                             const float* __restrict__ bias2,
                                             void* __restrict__ outv, int n) {
    constexpr int M = (MODE == 3) ? 40 : 64;   // matvec width
    __shared__ float sW[64 * 64];
    __shared__ float sV[4][64];
    if (MODE >= 2) {
        for (int i = threadIdx.x; i < 16 * M; i += 256)
            ((float4*)sW)[i] = ((const float4*)Wn)[i];
        __syncthreads();
    }
    int wid = threadIdx.x >> 6, lane = threadIdx.x & 63;
    int node = blockIdx.x * 4 + wid;
    if (node >= n) return;
    int beg = rowptr[node], end = rowptr[node + 1];
    int eg = lane >> 3;      // edge slot 0..7
    int fl = lane & 7;       // half8 slot 0..7
    float2 a[4] = {};
    int jj = beg + eg;
    for (; jj + 8 < end; jj += 16) {         // 16 edges/iter, 2 gathers in flight
        int s0 = csr_src[jj], s1 = csr_src[jj + 8];
        uint4 r0 = *(const uint4*)(g + ((size_t)s0 << 6) + (fl << 3));
        uint4 r1 = *(const uint4*)(g + ((size_t)s1 << 6) + (fl << 3));
        ACC8(r0); ACC8(r1);
    }
    if (jj < end) {
        int s = csr_src[jj];
        uint4 r = *(const uint4*)(g + ((size_t)s << 6) + (fl << 3));
        ACC8(r);
    }
    // reduce the 8 edge groups (lane bits 3,4,5)
#pragma unroll
    for (int m = 8; m <= 32; m <<= 1) {
#pragma unroll
        for (int k = 0; k < 4; ++k) {
            a[k].x += __shfl_xor(a[k].x, m);
            a[k].y += __shfl_xor(a[k].y, m);
        }
    }
    float di = dinv[node];
    if (eg == 0) {
        uint4 r = *(const uint4*)(g + ((size_t)node << 6) + (fl << 3));  // self
        ACC8(r);
        float t[8] = { a[0].x, a[0].y, a[1].x, a[1].y, a[2].x, a[2].y, a[3].x, a[3].y };
        if (MODE == 1) {
            union { uint4 u; __half2 h[4]; } P;
#pragma unroll
            for (int k = 0; k < 4; ++k) {
                float o0 = fmaxf(t[2 * k]     * di + bias[(fl << 3) + 2 * k],     0.f) * di;
                float o1 = fmaxf(t[2 * k + 1] * di + bias[(fl << 3) + 2 * k + 1], 0.f) * di;
                P.h[k] = __float22half2_rn(make_float2(o0, o1));
            }
            *(uint4*)((__half*)outv + ((size_t)node << 6) + (fl << 3)) = P.u;
        } else if (MODE == 2) {
#pragma unroll
            for (int k = 0; k < 8; ++k)
                sV[wid][(fl << 3) + k] = fmaxf(t[k] * di + bias[(fl << 3) + k], 0.f);
        } else {
#pragma unroll
            for (int k = 0; k < 8; ++k)
                sV[wid][(fl << 3) + k] = t[k] * di;
        }
    }
    if (MODE >= 2) {
        // same-wave ds_write -> ds_read ordering
        asm volatile("s_waitcnt lgkmcnt(0)" ::: "memory");
        float acc = 0.f;
#pragma unroll
        for (int kk = 0; kk < 16; ++kk) {
            float4 v4 = *(const float4*)&sV[wid][kk << 2];
            acc += v4.x * sW[(kk * 4 + 0) * M + lane];
            acc += v4.y * sW[(kk * 4 + 1) * M + lane];
            acc += v4.z * sW[(kk * 4 + 2) * M + lane];
            acc += v4.w * sW[(kk * 4 + 3) * M + lane];
        }
        if (MODE == 2) {
            ((__half*)outv)[((size_t)node << 6) + lane] = __float2half(acc * di);
        } else if (lane < 40) {
            ((float*)outv)[(size_t)node * 40 + lane] = acc + bias2[lane];
        }
    }
}

extern "C" void kernel_launch(void* const* d_in, const int* in_sizes, int n_in,
                              void* d_out, int out_size, void* d_ws, size_t ws_size,
                              hipStream_t stream) {
    const float* x  = (const float*)d_in[0];
    const int*   ei = (const int*)d_in[1];   // [2 x E]: row0 = src, row1 = dst
    const float* W1 = (const float*)d_in[2];
    const float* b1 = (const float*)d_in[3];
    const float* W2 = (const float*)d_in[4];
    const float* b2 = (const float*)d_in[5];
    const float* W3 = (const float*)d_in[6];
    const float* b3 = (const float*)d_in[7];
    float* out = (float*)d_out;

    const int* src = ei;
    const int* dst = ei + NE;

    // workspace: deg | rowptr | cursor | bsum[512] | boff[512] | dinv | csr_src[NE] |
    //            gA (half N*64) | gB (half N*64)          (~34 MB)
    int*    deg     = (int*)d_ws;
    int*    rowptr  = deg + NPAD;
    int*    cursor  = rowptr + NPAD;
    int*    bsum    = cursor + NPAD;
    int*    boff    = bsum + 512;
    float*  dinv    = (float*)(boff + 512);
    int*    csr_src = (int*)(dinv + NPAD);
    __half* gA      = (__half*)(csr_src + NE);
    __half* gB      = gA + (size_t)NN * 64;

    const int B = 256;
    const int gE = (NE + B - 1) / B;
    const int gG = (NN + 31) / 32;
    const int gA_blk = (NN + 3) / 4;      // 4 nodes (waves) per block
    const int nb = (NN + 255) / 256;

    // ---- CSR build + norm ----
    hipMemsetAsync(deg, 0, NPAD * sizeof(int), stream);
    hipMemsetAsync(cursor, 0, NPAD * sizeof(int), stream);
    k_deg_count<<<gE, B, 0, stream>>>(dst, deg, NE);
    k_part<<<nb, 256, 0, stream>>>(deg, bsum, NN);
    k_top<<<1, 512, 0, stream>>>(bsum, boff, nb, rowptr, NN, NE);
    k_write<<<nb, 256, 0, stream>>>(deg, boff, rowptr, dinv, NN);
    k_fill<<<gE, B, 0, stream>>>(src, dst, rowptr, cursor, csr_src, NE);

    // ---- layer 1 GEMM (scaled fp16 out): gA = fp16(dinv .* (x @ W1)) ----
    k_gemm1<<<gG, B, 0, stream>>>(x, W1, dinv, gA, NN);
    // ---- AGG1 fused: gB = fp16(dinv .* (relu(dinv*t + b1) @ W2)) ----
    k_agg<2><<<gA_blk, B, 0, stream>>>(rowptr, csr_src, gA, dinv, b1, W2, nullptr, gB, NN);
    // ---- AGG2: gA = fp16(dinv .* relu(dinv*t + b2)) ----
    k_agg<1><<<gA_blk, B, 0, stream>>>(rowptr, csr_src, gB, dinv, b2, nullptr, nullptr, gA, NN);
    // ---- AGG3 fused: out = (dinv*t) @ W3 + b3 ----
    k_agg<3><<<gA_blk, B, 0, stream>>>(rowptr, csr_src, gA, dinv, nullptr, W3, b3, out, NN);
}